// Round 2
// 387.973 us; speedup vs baseline: 1.0940x; 1.0940x over previous
//
#include <hip/hip_runtime.h>

// TripleBatchTransform: roll(move) -> +noise*0.04 -> pairwise mean-pool
// (written twice) -> per-row standardize.
//
// Math: pooled p[j] = 0.5*(z[2j]+z[2j+1]), z[i] = x[(i-move)%L] + 0.04*noise[i].
// Repeated-twice signal has mean/std identical to mean/std over pooled values,
// so: pass 1 reduces sum/sumsq of pooled; pass 2 recomputes pooled (x re-read
// is L3-resident: whole input = 204.8 MB < 256 MB Infinity Cache) and writes
// (p-mu)*inv_sd to both output slots.
//
// v2: MLP fix. rocprof showed 2.15 TB/s @ VGPR=20 -> latency-bound with ~1
// outstanding 8B load per wave. Fast path (mv%4==0 && L%4==0, true for the
// bench's mv=100): each "unit" u covers 2 pooled pairs = one aligned float4
// x-load + one float4 noise-load + one aligned float4 store; manual 4x unroll
// puts 8 independent 16B loads in flight per wave per iteration.
// (Resubmitted unchanged after an infra-side container failure in round 1;
// bounds audit: s = 4u - mv is always in [0, L-4] and 16B-aligned.)

#define THREADS 1024
#define NWAVES (THREADS / 64)

__global__ __launch_bounds__(THREADS) void tbt_kernel(
    const float* __restrict__ x,
    const float* __restrict__ noise,
    const int* __restrict__ movep,
    float* __restrict__ out,
    int L)
{
    const int b   = blockIdx.x;
    const int tid = threadIdx.x;
    const int J   = L >> 1;  // pooled count per row

    int mv = movep[0];
    mv %= L;
    if (mv < 0) mv += L;

    const float* __restrict__ xrow = x + (size_t)b * (size_t)L;
    float* __restrict__ orow       = out + (size_t)b * (size_t)L;

    // mv%4==0 && L%4==0: unit u -> x[4u-mv .. 4u-mv+3] (16B aligned, no
    // mid-unit wrap since s is a multiple of 4 and s <= L-4), noise[4u..4u+3],
    // out[4u..4u+3]. Wave-uniform branch.
    const bool fast4 = ((mv & 3) == 0) && ((L & 3) == 0);
    const bool fast2 = ((mv & 1) == 0) && ((L & 1) == 0);

    float sum = 0.f, sumsq = 0.f;

    if (fast4) {
        const int U = J >> 1;  // float4 units per row (2 pooled each)
        int u = tid;
        for (; u + 3 * THREADS < U; u += 4 * THREADS) {
            int s0 = 4 * (u              ) - mv; if (s0 < 0) s0 += L;
            int s1 = 4 * (u +     THREADS) - mv; if (s1 < 0) s1 += L;
            int s2 = 4 * (u + 2 * THREADS) - mv; if (s2 < 0) s2 += L;
            int s3 = 4 * (u + 3 * THREADS) - mv; if (s3 < 0) s3 += L;
            float4 v0 = *(const float4*)(xrow + s0);
            float4 v1 = *(const float4*)(xrow + s1);
            float4 v2 = *(const float4*)(xrow + s2);
            float4 v3 = *(const float4*)(xrow + s3);
            float4 n0 = *(const float4*)(noise + 4 * (u              ));
            float4 n1 = *(const float4*)(noise + 4 * (u +     THREADS));
            float4 n2 = *(const float4*)(noise + 4 * (u + 2 * THREADS));
            float4 n3 = *(const float4*)(noise + 4 * (u + 3 * THREADS));
            float p0 = 0.5f * (v0.x + v0.y) + 0.02f * (n0.x + n0.y);
            float p1 = 0.5f * (v0.z + v0.w) + 0.02f * (n0.z + n0.w);
            float p2 = 0.5f * (v1.x + v1.y) + 0.02f * (n1.x + n1.y);
            float p3 = 0.5f * (v1.z + v1.w) + 0.02f * (n1.z + n1.w);
            float p4 = 0.5f * (v2.x + v2.y) + 0.02f * (n2.x + n2.y);
            float p5 = 0.5f * (v2.z + v2.w) + 0.02f * (n2.z + n2.w);
            float p6 = 0.5f * (v3.x + v3.y) + 0.02f * (n3.x + n3.y);
            float p7 = 0.5f * (v3.z + v3.w) + 0.02f * (n3.z + n3.w);
            sum   += ((p0 + p1) + (p2 + p3)) + ((p4 + p5) + (p6 + p7));
            sumsq += ((p0 * p0 + p1 * p1) + (p2 * p2 + p3 * p3))
                   + ((p4 * p4 + p5 * p5) + (p6 * p6 + p7 * p7));
        }
        for (; u < U; u += THREADS) {
            int s = 4 * u - mv; if (s < 0) s += L;
            float4 v = *(const float4*)(xrow + s);
            float4 n = *(const float4*)(noise + 4 * u);
            float p0 = 0.5f * (v.x + v.y) + 0.02f * (n.x + n.y);
            float p1 = 0.5f * (v.z + v.w) + 0.02f * (n.z + n.w);
            sum   += p0 + p1;
            sumsq += p0 * p0 + p1 * p1;
        }
        // L%4==0 => J even => no pooled-pair tail.
    } else {
        for (int j = tid; j < J; j += THREADS) {
            int s = 2 * j - mv;
            if (s < 0) s += L;
            float a, c;
            if (fast2) {
                float2 v = *(const float2*)(xrow + s);
                a = v.x; c = v.y;
            } else {
                int s1 = s + 1; if (s1 >= L) s1 -= L;
                a = xrow[s]; c = xrow[s1];
            }
            float2 nv = *(const float2*)(noise + 2 * j);
            float p = 0.5f * (a + c + 0.04f * (nv.x + nv.y));
            sum   += p;
            sumsq += p * p;
        }
    }

    // wave (64-lane) reduction
    #pragma unroll
    for (int off = 32; off > 0; off >>= 1) {
        sum   += __shfl_down(sum,   off, 64);
        sumsq += __shfl_down(sumsq, off, 64);
    }

    __shared__ float s_sum[NWAVES], s_sq[NWAVES];
    __shared__ float s_mu, s_isd;
    const int wave = tid >> 6;
    const int lane = tid & 63;
    if (lane == 0) { s_sum[wave] = sum; s_sq[wave] = sumsq; }
    __syncthreads();
    if (tid == 0) {
        float ts = 0.f, tq = 0.f;
        #pragma unroll
        for (int w = 0; w < NWAVES; ++w) { ts += s_sum[w]; tq += s_sq[w]; }
        float invJ = 1.0f / (float)J;
        float mu   = ts * invJ;
        float var  = tq * invJ - mu * mu;
        s_mu  = mu;
        s_isd = rsqrtf(fmaxf(var, 1e-30f));
    }
    __syncthreads();
    const float mu  = s_mu;
    const float isd = s_isd;

    // pass 2: recompute pooled (x re-read hits L3), write both slots
    if (fast4) {
        const int U = J >> 1;
        int u = tid;
        for (; u + 3 * THREADS < U; u += 4 * THREADS) {
            int s0 = 4 * (u              ) - mv; if (s0 < 0) s0 += L;
            int s1 = 4 * (u +     THREADS) - mv; if (s1 < 0) s1 += L;
            int s2 = 4 * (u + 2 * THREADS) - mv; if (s2 < 0) s2 += L;
            int s3 = 4 * (u + 3 * THREADS) - mv; if (s3 < 0) s3 += L;
            float4 v0 = *(const float4*)(xrow + s0);
            float4 v1 = *(const float4*)(xrow + s1);
            float4 v2 = *(const float4*)(xrow + s2);
            float4 v3 = *(const float4*)(xrow + s3);
            float4 n0 = *(const float4*)(noise + 4 * (u              ));
            float4 n1 = *(const float4*)(noise + 4 * (u +     THREADS));
            float4 n2 = *(const float4*)(noise + 4 * (u + 2 * THREADS));
            float4 n3 = *(const float4*)(noise + 4 * (u + 3 * THREADS));
            float r0 = (0.5f * (v0.x + v0.y) + 0.02f * (n0.x + n0.y) - mu) * isd;
            float r1 = (0.5f * (v0.z + v0.w) + 0.02f * (n0.z + n0.w) - mu) * isd;
            float r2 = (0.5f * (v1.x + v1.y) + 0.02f * (n1.x + n1.y) - mu) * isd;
            float r3 = (0.5f * (v1.z + v1.w) + 0.02f * (n1.z + n1.w) - mu) * isd;
            float r4 = (0.5f * (v2.x + v2.y) + 0.02f * (n2.x + n2.y) - mu) * isd;
            float r5 = (0.5f * (v2.z + v2.w) + 0.02f * (n2.z + n2.w) - mu) * isd;
            float r6 = (0.5f * (v3.x + v3.y) + 0.02f * (n3.x + n3.y) - mu) * isd;
            float r7 = (0.5f * (v3.z + v3.w) + 0.02f * (n3.z + n3.w) - mu) * isd;
            *(float4*)(orow + 4 * (u              )) = make_float4(r0, r0, r1, r1);
            *(float4*)(orow + 4 * (u +     THREADS)) = make_float4(r2, r2, r3, r3);
            *(float4*)(orow + 4 * (u + 2 * THREADS)) = make_float4(r4, r4, r5, r5);
            *(float4*)(orow + 4 * (u + 3 * THREADS)) = make_float4(r6, r6, r7, r7);
        }
        for (; u < U; u += THREADS) {
            int s = 4 * u - mv; if (s < 0) s += L;
            float4 v = *(const float4*)(xrow + s);
            float4 n = *(const float4*)(noise + 4 * u);
            float r0 = (0.5f * (v.x + v.y) + 0.02f * (n.x + n.y) - mu) * isd;
            float r1 = (0.5f * (v.z + v.w) + 0.02f * (n.z + n.w) - mu) * isd;
            *(float4*)(orow + 4 * u) = make_float4(r0, r0, r1, r1);
        }
    } else {
        for (int j = tid; j < J; j += THREADS) {
            int s = 2 * j - mv;
            if (s < 0) s += L;
            float a, c;
            if (fast2) {
                float2 v = *(const float2*)(xrow + s);
                a = v.x; c = v.y;
            } else {
                int s1 = s + 1; if (s1 >= L) s1 -= L;
                a = xrow[s]; c = xrow[s1];
            }
            float2 nv = *(const float2*)(noise + 2 * j);
            float p = 0.5f * (a + c + 0.04f * (nv.x + nv.y));
            float r = (p - mu) * isd;
            *(float2*)(orow + 2 * j) = make_float2(r, r);
        }
    }
}

extern "C" void kernel_launch(void* const* d_in, const int* in_sizes, int n_in,
                              void* d_out, int out_size, void* d_ws, size_t ws_size,
                              hipStream_t stream) {
    const float* x     = (const float*)d_in[0];
    const float* noise = (const float*)d_in[1];
    const int*   move  = (const int*)d_in[2];
    float*       out   = (float*)d_out;

    const int L = in_sizes[1];             // 100000
    const int B = in_sizes[0] / L;         // 512

    tbt_kernel<<<B, THREADS, 0, stream>>>(x, noise, move, out, L);
}

// Round 3
// 349.001 us; speedup vs baseline: 1.2161x; 1.1117x over previous
//
#include <hip/hip_runtime.h>

// TripleBatchTransform: roll(move) -> +noise*0.04 -> pairwise mean-pool
// (written twice) -> per-row standardize.
//
// Math: pooled p[j] = 0.5*(z[2j]+z[2j+1]), z[i] = x[(i-move)%L] + 0.04*noise[i].
// Repeated-twice signal has mean/std == mean/std over pooled values.
//
// v3: register-resident pooled. v2 counters showed traffic already ideal
// (FETCH 210 MB = x once, WRITE 201 MB = out once) but only 2.65 TB/s:
// pass 2 re-read 205 MB of x from L3 while streaming 201 MB of writes, plus
// a full barrier drain between phases. Fix: each thread keeps its ~50 pooled
// values in a fully-unrolled register array across the barrier; pass 2 is a
// pure store stream (no x/noise re-read, no load latency).
// 50 p-regs + machinery stays under the 128-VGPR hard cap for 1024-thread
// blocks (131072 regs/CU). Indices into p[] are all compile-time (unrolled)
// so it stays in VGPRs, not scratch.

#define THREADS 1024
#define NWAVES (THREADS / 64)
#define KMAX 25  // max float4-units per thread on the register path

__global__ __launch_bounds__(THREADS) void tbt_kernel(
    const float* __restrict__ x,
    const float* __restrict__ noise,
    const int* __restrict__ movep,
    float* __restrict__ out,
    int L)
{
    const int b   = blockIdx.x;
    const int tid = threadIdx.x;
    const int J   = L >> 1;  // pooled count per row

    int mv = movep[0];
    mv %= L;
    if (mv < 0) mv += L;

    const float* __restrict__ xrow = x + (size_t)b * (size_t)L;
    float* __restrict__ orow       = out + (size_t)b * (size_t)L;

    // mv%4==0 && L%4==0: unit u -> x[4u-mv .. 4u-mv+3] (16B aligned, never
    // wraps mid-unit since s stays a multiple of 4 in [0, L-4]).
    const bool fast4 = ((mv & 3) == 0) && ((L & 3) == 0);
    const bool fast2 = ((mv & 1) == 0) && ((L & 1) == 0);

    const int U  = J >> 1;                      // float4 units per row
    const int nk = (U + THREADS - 1) / THREADS; // units per thread (ceil)

    float sum = 0.f, sumsq = 0.f;

    if (fast4 && nk <= KMAX) {
        // ---------- register-resident path ----------
        float p[2 * KMAX];

        #pragma unroll
        for (int k = 0; k < KMAX; ++k) {
            const int u = tid + k * THREADS;
            if (u < U) {
                int s = 4 * u - mv; if (s < 0) s += L;
                float4 v = *(const float4*)(xrow + s);
                float4 n = *(const float4*)(noise + 4 * u);
                float a = 0.5f * (v.x + v.y) + 0.02f * (n.x + n.y);
                float c = 0.5f * (v.z + v.w) + 0.02f * (n.z + n.w);
                p[2 * k]     = a;
                p[2 * k + 1] = c;
                sum   += a + c;
                sumsq += a * a + c * c;
            }
        }

        // wave (64-lane) reduction
        #pragma unroll
        for (int off = 32; off > 0; off >>= 1) {
            sum   += __shfl_down(sum,   off, 64);
            sumsq += __shfl_down(sumsq, off, 64);
        }

        __shared__ float s_sum[NWAVES], s_sq[NWAVES];
        __shared__ float s_mu, s_isd;
        const int wave = tid >> 6;
        const int lane = tid & 63;
        if (lane == 0) { s_sum[wave] = sum; s_sq[wave] = sumsq; }
        __syncthreads();
        if (tid == 0) {
            float ts = 0.f, tq = 0.f;
            #pragma unroll
            for (int w = 0; w < NWAVES; ++w) { ts += s_sum[w]; tq += s_sq[w]; }
            float invJ = 1.0f / (float)J;
            float mu   = ts * invJ;
            float var  = tq * invJ - mu * mu;
            s_mu  = mu;
            s_isd = rsqrtf(fmaxf(var, 1e-30f));
        }
        __syncthreads();
        const float mu  = s_mu;
        const float isd = s_isd;

        // pass 2: pure store stream from registers
        #pragma unroll
        for (int k = 0; k < KMAX; ++k) {
            const int u = tid + k * THREADS;
            if (u < U) {
                float r0 = (p[2 * k]     - mu) * isd;
                float r1 = (p[2 * k + 1] - mu) * isd;
                *(float4*)(orow + 4 * u) = make_float4(r0, r0, r1, r1);
            }
        }
        return;
    }

    // ---------- generic fallback: two-pass recompute ----------
    for (int j = tid; j < J; j += THREADS) {
        int s = 2 * j - mv;
        if (s < 0) s += L;
        float a, c;
        if (fast2) {
            float2 v = *(const float2*)(xrow + s);
            a = v.x; c = v.y;
        } else {
            int s1 = s + 1; if (s1 >= L) s1 -= L;
            a = xrow[s]; c = xrow[s1];
        }
        float2 nv = *(const float2*)(noise + 2 * j);
        float p = 0.5f * (a + c + 0.04f * (nv.x + nv.y));
        sum   += p;
        sumsq += p * p;
    }

    #pragma unroll
    for (int off = 32; off > 0; off >>= 1) {
        sum   += __shfl_down(sum,   off, 64);
        sumsq += __shfl_down(sumsq, off, 64);
    }

    __shared__ float f_sum[NWAVES], f_sq[NWAVES];
    __shared__ float f_mu, f_isd;
    const int wave = tid >> 6;
    const int lane = tid & 63;
    if (lane == 0) { f_sum[wave] = sum; f_sq[wave] = sumsq; }
    __syncthreads();
    if (tid == 0) {
        float ts = 0.f, tq = 0.f;
        #pragma unroll
        for (int w = 0; w < NWAVES; ++w) { ts += f_sum[w]; tq += f_sq[w]; }
        float invJ = 1.0f / (float)J;
        float mu   = ts * invJ;
        float var  = tq * invJ - mu * mu;
        f_mu  = mu;
        f_isd = rsqrtf(fmaxf(var, 1e-30f));
    }
    __syncthreads();
    const float mu  = f_mu;
    const float isd = f_isd;

    for (int j = tid; j < J; j += THREADS) {
        int s = 2 * j - mv;
        if (s < 0) s += L;
        float a, c;
        if (fast2) {
            float2 v = *(const float2*)(xrow + s);
            a = v.x; c = v.y;
        } else {
            int s1 = s + 1; if (s1 >= L) s1 -= L;
            a = xrow[s]; c = xrow[s1];
        }
        float2 nv = *(const float2*)(noise + 2 * j);
        float p = 0.5f * (a + c + 0.04f * (nv.x + nv.y));
        float r = (p - mu) * isd;
        *(float2*)(orow + 2 * j) = make_float2(r, r);
    }
}

extern "C" void kernel_launch(void* const* d_in, const int* in_sizes, int n_in,
                              void* d_out, int out_size, void* d_ws, size_t ws_size,
                              hipStream_t stream) {
    const float* x     = (const float*)d_in[0];
    const float* noise = (const float*)d_in[1];
    const int*   move  = (const int*)d_in[2];
    float*       out   = (float*)d_out;

    const int L = in_sizes[1];             // 100000
    const int B = in_sizes[0] / L;         // 512

    tbt_kernel<<<B, THREADS, 0, stream>>>(x, noise, move, out, L);
}